// Round 6
// baseline (2108.808 us; speedup 1.0000x reference)
//
#include <hip/hip_runtime.h>
#include <hip/hip_bf16.h>

#define HID 768
#define NHEADS 12
#define HDIM 64
#define SEQ 4096
#define BB 2
#define MTOT (BB * SEQ)   // 8192 rows

typedef __attribute__((ext_vector_type(8))) short bf16x8;
typedef __attribute__((ext_vector_type(16))) float f32x16;

#define LOG2E 1.4426950408889634f

__device__ inline unsigned pack2bf(float a, float b) {
    __hip_bfloat162 h = __float22bfloat162_rn(float2{a, b});
    return *(unsigned*)&h;
}

// ---------------------------------------------------------------------------
// Kernel 0a: cast X fp32 -> bf16. grid 3072, block 256, 8 elems/thread.
// ---------------------------------------------------------------------------
__global__ __launch_bounds__(256) void cast_x_kernel(
    const float* __restrict__ X, __hip_bfloat16* __restrict__ Xb)
{
    const size_t i = ((size_t)blockIdx.x * 256 + threadIdx.x) * 8;
    const float4 x0 = *(const float4*)(X + i);
    const float4 x1 = *(const float4*)(X + i + 4);
    unsigned u[4];
    u[0] = pack2bf(x0.x, x0.y);
    u[1] = pack2bf(x0.z, x0.w);
    u[2] = pack2bf(x1.x, x1.y);
    u[3] = pack2bf(x1.z, x1.w);
    *(uint4*)(Xb + i) = *(uint4*)u;
}

// ---------------------------------------------------------------------------
// Kernel 0b: pack weights: W[in][out] fp32 -> Wt[out(global)][in] bf16.
// z=0..3 selects Wq,Wk,Wv,Wo; Wo at row offset 2304.
// ---------------------------------------------------------------------------
__global__ __launch_bounds__(256) void pack_w_kernel(
    const float* __restrict__ Wq, const float* __restrict__ Wk,
    const float* __restrict__ Wv, const float* __restrict__ Wo,
    __hip_bfloat16* __restrict__ Wt)
{
    const int z = blockIdx.z;
    const float* __restrict__ W = (z == 0) ? Wq : (z == 1) ? Wk : (z == 2) ? Wv : Wo;
    const int in0  = blockIdx.x * 64;
    const int out0 = blockIdx.y * 64;
    const int t = threadIdx.x;

    __shared__ float T[64][65];
#pragma unroll
    for (int i = 0; i < 4; ++i) {
        const int idx = t + 256 * i;
        const int row = idx >> 4;
        const int c4  = (idx & 15) << 2;
        const float4 v = *(const float4*)(W + (size_t)(in0 + row) * HID + out0 + c4);
        T[row][c4 + 0] = v.x; T[row][c4 + 1] = v.y;
        T[row][c4 + 2] = v.z; T[row][c4 + 3] = v.w;
    }
    __syncthreads();

    const int o  = t >> 2;
    const int cb = (t & 3) << 4;
    __hip_bfloat16 tmp[16];
#pragma unroll
    for (int k = 0; k < 16; ++k)
        tmp[k] = __float2bfloat16(T[cb + k][o]);
    __hip_bfloat16* __restrict__ dst =
        Wt + (size_t)(z * HID + out0 + o) * HID + in0 + cb;
    *(uint4*)(dst)     = *(uint4*)(&tmp[0]);
    *(uint4*)(dst + 8) = *(uint4*)(&tmp[8]);
}

// ---------------------------------------------------------------------------
// Kernel 1: fused QKV MFMA GEMM. Q,K -> bf16 [b,h,s,64]; V -> bf16 [b,h,64,s]
// (transposed in-epilogue via LDS). grid (18, 64), block 256, 128x128, BK=64.
// ---------------------------------------------------------------------------
__global__ __launch_bounds__(256) void qkv_mfma_kernel(
    const __hip_bfloat16* __restrict__ Xb, const __hip_bfloat16* __restrict__ Wt,
    const float* __restrict__ bq, const float* __restrict__ bk,
    const float* __restrict__ bv,
    __hip_bfloat16* __restrict__ Qo, __hip_bfloat16* __restrict__ Ko,
    __hip_bfloat16* __restrict__ Vo)
{
    const int nblk = blockIdx.x;          // 0..17
    const int z  = nblk / 6;              // 0=Q,1=K,2=V
    const int f0 = (nblk % 6) * 128;      // feature base within segment
    const int n0 = nblk * 128;            // row base in Wt
    const int m0 = blockIdx.y * 128;

    const float* __restrict__ bias = (z == 0) ? bq : (z == 1) ? bk : bv;

    const int t    = threadIdx.x;
    const int w    = t >> 6;
    const int lane = t & 63;
    const int col  = lane & 31;
    const int g    = lane >> 5;
    const int wm   = w & 1;
    const int wn   = w >> 1;

    __shared__ __hip_bfloat16 smem[2 * 128 * 72];   // As | Bs; Ts overlays both
    __hip_bfloat16 (*As)[72] = (__hip_bfloat16(*)[72])smem;
    __hip_bfloat16 (*Bs)[72] = (__hip_bfloat16(*)[72])(smem + 128 * 72);

    f32x16 acc[2][2];
#pragma unroll
    for (int mt = 0; mt < 2; ++mt)
#pragma unroll
        for (int nt = 0; nt < 2; ++nt)
#pragma unroll
            for (int r = 0; r < 16; ++r) acc[mt][nt][r] = 0.f;

    for (int k0 = 0; k0 < HID; k0 += 64) {
        __syncthreads();
#pragma unroll
        for (int i = 0; i < 4; ++i) {
            const int idx = t + 256 * i;     // 0..1023
            const int row = idx >> 3;        // 0..127
            const int c8  = (idx & 7) << 3;  // 0..56
            *(uint4*)&As[row][c8] = *(const uint4*)(Xb + (size_t)(m0 + row) * HID + k0 + c8);
            *(uint4*)&Bs[row][c8] = *(const uint4*)(Wt + (size_t)(n0 + row) * HID + k0 + c8);
        }
        __syncthreads();
#pragma unroll
        for (int kh = 0; kh < 4; ++kh) {
            const int ko = 16 * kh + 8 * g;
            const bf16x8 a0 = *(const bf16x8*)&As[64 * wm + col][ko];
            const bf16x8 a1 = *(const bf16x8*)&As[64 * wm + 32 + col][ko];
            const bf16x8 b0 = *(const bf16x8*)&Bs[64 * wn + col][ko];
            const bf16x8 b1 = *(const bf16x8*)&Bs[64 * wn + 32 + col][ko];
            acc[0][0] = __builtin_amdgcn_mfma_f32_32x32x16_bf16(a0, b0, acc[0][0], 0, 0, 0);
            acc[0][1] = __builtin_amdgcn_mfma_f32_32x32x16_bf16(a0, b1, acc[0][1], 0, 0, 0);
            acc[1][0] = __builtin_amdgcn_mfma_f32_32x32x16_bf16(a1, b0, acc[1][0], 0, 0, 0);
            acc[1][1] = __builtin_amdgcn_mfma_f32_32x32x16_bf16(a1, b1, acc[1][1], 0, 0, 0);
        }
    }

    if (z < 2) {
        __hip_bfloat16* __restrict__ Out = (z == 0) ? Qo : Ko;
        const int h = (f0 >> 6) + wn;
#pragma unroll
        for (int mt = 0; mt < 2; ++mt)
#pragma unroll
            for (int nt = 0; nt < 2; ++nt) {
                const int d = 32 * nt + col;
                const float bsv = bias[f0 + 64 * wn + d];
#pragma unroll
                for (int r = 0; r < 16; ++r) {
                    const int m = m0 + 64 * wm + 32 * mt + (r & 3) + 8 * (r >> 2) + 4 * g;
                    const int b = m >> 12;
                    const int s = m & (SEQ - 1);
                    Out[(((size_t)(b * NHEADS + h)) * SEQ + s) * HDIM + d] =
                        __float2bfloat16(acc[mt][nt][r] + bsv);
                }
            }
    } else {
        // V: transpose 128x128 tile via LDS, write Vt [bh][d][s]
        __syncthreads();   // K-loop LDS reads done before overlay
        __hip_bfloat16 (*Ts)[136] = (__hip_bfloat16(*)[136])smem;  // 34816 B
#pragma unroll
        for (int mt = 0; mt < 2; ++mt)
#pragma unroll
            for (int nt = 0; nt < 2; ++nt) {
                const int nloc = 64 * wn + 32 * nt + col;
                const float bsv = bias[f0 + nloc];
#pragma unroll
                for (int rg = 0; rg < 4; ++rg) {
                    const int mbase = 64 * wm + 32 * mt + 8 * rg + 4 * g;
                    unsigned pu[2];
                    pu[0] = pack2bf(acc[mt][nt][4 * rg + 0] + bsv,
                                    acc[mt][nt][4 * rg + 1] + bsv);
                    pu[1] = pack2bf(acc[mt][nt][4 * rg + 2] + bsv,
                                    acc[mt][nt][4 * rg + 3] + bsv);
                    *(uint2*)&Ts[nloc][mbase] = *(uint2*)pu;
                }
            }
        __syncthreads();
        const int nloc = t >> 1;
        const int half = t & 1;
        const int hh = (f0 >> 6) + (nloc >> 6);
        const int d  = nloc & 63;
        const int bb = m0 >> 12;
        const int s0 = m0 & (SEQ - 1);
        __hip_bfloat16* __restrict__ dst =
            Vo + (((size_t)(bb * NHEADS + hh)) * HDIM + d) * SEQ + s0 + 64 * half;
        const __hip_bfloat16* srcp = &Ts[nloc][64 * half];
#pragma unroll
        for (int j = 0; j < 8; ++j)
            *(uint4*)(dst + 8 * j) = *(const uint4*)(srcp + 8 * j);
    }
}

// ---------------------------------------------------------------------------
// Kernel 2: MFMA flash attention (S^T-swap + shuffle P-transform, K-split).
// exp2-folded softmax, no clamp. 4 blocks/CU via launch_bounds(256,4).
// ---------------------------------------------------------------------------
__global__ __launch_bounds__(256, 4) void attn_kernel(
    const __hip_bfloat16* __restrict__ Qb, const __hip_bfloat16* __restrict__ Kb,
    const __hip_bfloat16* __restrict__ Vt, const float* __restrict__ mask,
    __hip_bfloat16* __restrict__ Op, float* __restrict__ lp)
{
    const int bh = blockIdx.y;
    const int b  = bh / NHEADS;
    const int h  = bh - b * NHEADS;
    const int kspan = SEQ / gridDim.z;
    const int kbeg  = blockIdx.z * kspan;

    const int t    = threadIdx.x;
    const int w    = t >> 6;
    const int lane = t & 63;
    const int col  = lane & 31;
    const int g    = lane >> 5;
    const int qw   = blockIdx.x * 256 + 64 * w;

    __shared__ __hip_bfloat16 Ks[64][72];
    __shared__ __hip_bfloat16 Vts[64][72];
    __shared__ float madd[64];   // premultiplied by log2(e)

    const __hip_bfloat16* __restrict__ Qh = Qb + (size_t)bh * SEQ * HDIM;
    const __hip_bfloat16* __restrict__ Kh = Kb + (size_t)bh * SEQ * HDIM;
    const __hip_bfloat16* __restrict__ Vh = Vt + (size_t)bh * HDIM * SEQ;

    bf16x8 bq[2][4];
#pragma unroll
    for (int mt = 0; mt < 2; ++mt)
#pragma unroll
        for (int kh = 0; kh < 4; ++kh)
            bq[mt][kh] = *(const bf16x8*)(Qh + (size_t)(qw + 32 * mt + col) * HDIM
                                          + 16 * kh + 8 * g);

    f32x16 O[2][2];
    float lac[2] = {0.f, 0.f};
#pragma unroll
    for (int mt = 0; mt < 2; ++mt)
#pragma unroll
        for (int dt = 0; dt < 2; ++dt)
#pragma unroll
            for (int r = 0; r < 16; ++r) O[mt][dt][r] = 0.f;

    const float kscale = 0.125f * LOG2E;

    for (int kt0 = 0; kt0 < kspan; kt0 += 64) {
        const int kt = kbeg + kt0;
        __syncthreads();
#pragma unroll
        for (int i = 0; i < 2; ++i) {
            const int idx = t + 256 * i;
            const int row = idx >> 3;
            const int c8  = (idx & 7) << 3;
            *(uint4*)&Ks[row][c8]  = *(const uint4*)(Kh + (size_t)(kt + row) * HDIM + c8);
            *(uint4*)&Vts[row][c8] = *(const uint4*)(Vh + (size_t)row * SEQ + kt + c8);
        }
        if (t < 64) madd[t] = (1.0f - mask[b * SEQ + kt + t]) * (-10000.0f * LOG2E);
        __syncthreads();

        f32x16 St[2][2];
#pragma unroll
        for (int mt = 0; mt < 2; ++mt)
#pragma unroll
            for (int nt = 0; nt < 2; ++nt)
#pragma unroll
                for (int r = 0; r < 16; ++r) St[mt][nt][r] = 0.f;

#pragma unroll
        for (int kh = 0; kh < 4; ++kh) {
            const bf16x8 ak0 = *(const bf16x8*)&Ks[col][16 * kh + 8 * g];
            const bf16x8 ak1 = *(const bf16x8*)&Ks[32 + col][16 * kh + 8 * g];
            St[0][0] = __builtin_amdgcn_mfma_f32_32x32x16_bf16(ak0, bq[0][kh], St[0][0], 0, 0, 0);
            St[1][0] = __builtin_amdgcn_mfma_f32_32x32x16_bf16(ak0, bq[1][kh], St[1][0], 0, 0, 0);
            St[0][1] = __builtin_amdgcn_mfma_f32_32x32x16_bf16(ak1, bq[0][kh], St[0][1], 0, 0, 0);
            St[1][1] = __builtin_amdgcn_mfma_f32_32x32x16_bf16(ak1, bq[1][kh], St[1][1], 0, 0, 0);
        }

#pragma unroll
        for (int mt = 0; mt < 2; ++mt) {
            unsigned g4x[2][4], g4y[2][4];
#pragma unroll
            for (int nt = 0; nt < 2; ++nt) {
#pragma unroll
                for (int b4 = 0; b4 < 4; ++b4) {
                    const float4 mm = *(const float4*)&madd[32 * nt + 8 * b4 + 4 * g];
                    const float p0 = __builtin_amdgcn_exp2f(fmaf(St[mt][nt][4 * b4 + 0], kscale, mm.x));
                    const float p1 = __builtin_amdgcn_exp2f(fmaf(St[mt][nt][4 * b4 + 1], kscale, mm.y));
                    const float p2 = __builtin_amdgcn_exp2f(fmaf(St[mt][nt][4 * b4 + 2], kscale, mm.z));
                    const float p3 = __builtin_amdgcn_exp2f(fmaf(St[mt][nt][4 * b4 + 3], kscale, mm.w));
                    lac[mt] += (p0 + p1) + (p2 + p3);
                    g4x[nt][b4] = pack2bf(p0, p1);
                    g4y[nt][b4] = pack2bf(p2, p3);
                }
            }
#pragma unroll
            for (int kh = 0; kh < 4; ++kh) {
                const int nt  = kh >> 1;
                const int khl = kh & 1;
                const unsigned lo_x = g4x[nt][2 * khl],     lo_y = g4y[nt][2 * khl];
                const unsigned hi_x = g4x[nt][2 * khl + 1], hi_y = g4y[nt][2 * khl + 1];
                const unsigned sx = g ? lo_x : hi_x;
                const unsigned sy = g ? lo_y : hi_y;
                const unsigned rx = (unsigned)__shfl_xor((int)sx, 32, 64);
                const unsigned ry = (unsigned)__shfl_xor((int)sy, 32, 64);
                union { unsigned u[4]; bf16x8 v; } au;
                if (g) { au.u[0] = rx; au.u[1] = ry; au.u[2] = hi_x; au.u[3] = hi_y; }
                else   { au.u[0] = lo_x; au.u[1] = lo_y; au.u[2] = rx; au.u[3] = ry; }
                const bf16x8 bv0 = *(const bf16x8*)&Vts[col][16 * kh + 8 * g];
                const bf16x8 bv1 = *(const bf16x8*)&Vts[32 + col][16 * kh + 8 * g];
                O[mt][0] = __builtin_amdgcn_mfma_f32_32x32x16_bf16(au.v, bv0, O[mt][0], 0, 0, 0);
                O[mt][1] = __builtin_amdgcn_mfma_f32_32x32x16_bf16(au.v, bv1, O[mt][1], 0, 0, 0);
            }
        }
    }

    const size_t opbase = (size_t)blockIdx.z * ((size_t)MTOT * HID);
#pragma unroll
    for (int mt = 0; mt < 2; ++mt) {
        const float l = lac[mt] + __shfl_xor(lac[mt], 32, 64);
        if (g == 0)
            lp[((size_t)blockIdx.z * (BB * NHEADS) + bh) * SEQ + qw + 32 * mt + col] = l;
#pragma unroll
        for (int dt = 0; dt < 2; ++dt)
#pragma unroll
            for (int r = 0; r < 16; ++r) {
                const int q = qw + 32 * mt + (r & 3) + 8 * (r >> 2) + 4 * g;
                const int d = 32 * dt + col;
                Op[opbase + ((size_t)b * SEQ + q) * HID + h * HDIM + d] =
                    __float2bfloat16(O[mt][dt][r]);
            }
    }
}

// ---------------------------------------------------------------------------
// Kernel 2b: combine K-split partials -> Ctx bf16. 8 elems/thread.
// ---------------------------------------------------------------------------
__global__ __launch_bounds__(256) void combine_kernel(
    const __hip_bfloat16* __restrict__ Op, const float* __restrict__ lp,
    __hip_bfloat16* __restrict__ Ctx, int KS)
{
    const size_t i = ((size_t)blockIdx.x * 256 + threadIdx.x) * 8;
    const int n   = (int)(i % HID);
    const int row = (int)(i / HID);
    const int h = n >> 6;
    const int b = row >> 12;
    const int q = row & (SEQ - 1);
    const int bh = b * NHEADS + h;

    float denom = 0.f;
    float o[8] = {};
    for (int kz = 0; kz < KS; ++kz) {
        denom += lp[((size_t)kz * (BB * NHEADS) + bh) * SEQ + q];
        uint4 u = *(const uint4*)(Op + (size_t)kz * ((size_t)MTOT * HID) + i);
        const __hip_bfloat16* e = (const __hip_bfloat16*)&u;
#pragma unroll
        for (int j = 0; j < 8; ++j) o[j] += __bfloat162float(e[j]);
    }
    const float inv = 1.0f / denom;
    unsigned u[4];
#pragma unroll
    for (int j = 0; j < 4; ++j)
        u[j] = pack2bf(o[2 * j] * inv, o[2 * j + 1] * inv);
    *(uint4*)(Ctx + i) = *(uint4*)u;
}

// ---------------------------------------------------------------------------
// Kernel 3: output projection MFMA + bias + residual -> Resid fp32.
// grid (6, 64), block 256.
// ---------------------------------------------------------------------------
__global__ __launch_bounds__(256) void out_mfma_kernel(
    const __hip_bfloat16* __restrict__ Cb, const __hip_bfloat16* __restrict__ Wto,
    const float* __restrict__ bo, const float* __restrict__ X,
    float* __restrict__ Resid)
{
    const int n0 = blockIdx.x * 128;
    const int m0 = blockIdx.y * 128;

    const int t    = threadIdx.x;
    const int w    = t >> 6;
    const int lane = t & 63;
    const int col  = lane & 31;
    const int g    = lane >> 5;
    const int wm   = w & 1;
    const int wn   = w >> 1;

    __shared__ __hip_bfloat16 As[128][72];
    __shared__ __hip_bfloat16 Bs[128][72];

    f32x16 acc[2][2];
#pragma unroll
    for (int mt = 0; mt < 2; ++mt)
#pragma unroll
        for (int nt = 0; nt < 2; ++nt)
#pragma unroll
            for (int r = 0; r < 16; ++r) acc[mt][nt][r] = 0.f;

    for (int k0 = 0; k0 < HID; k0 += 64) {
        __syncthreads();
#pragma unroll
        for (int i = 0; i < 4; ++i) {
            const int idx = t + 256 * i;
            const int row = idx >> 3;
            const int c8  = (idx & 7) << 3;
            *(uint4*)&As[row][c8] = *(const uint4*)(Cb  + (size_t)(m0 + row) * HID + k0 + c8);
            *(uint4*)&Bs[row][c8] = *(const uint4*)(Wto + (size_t)(n0 + row) * HID + k0 + c8);
        }
        __syncthreads();
#pragma unroll
        for (int kh = 0; kh < 4; ++kh) {
            const int ko = 16 * kh + 8 * g;
            const bf16x8 a0 = *(const bf16x8*)&As[64 * wm + col][ko];
            const bf16x8 a1 = *(const bf16x8*)&As[64 * wm + 32 + col][ko];
            const bf16x8 b0 = *(const bf16x8*)&Bs[64 * wn + col][ko];
            const bf16x8 b1 = *(const bf16x8*)&Bs[64 * wn + 32 + col][ko];
            acc[0][0] = __builtin_amdgcn_mfma_f32_32x32x16_bf16(a0, b0, acc[0][0], 0, 0, 0);
            acc[0][1] = __builtin_amdgcn_mfma_f32_32x32x16_bf16(a0, b1, acc[0][1], 0, 0, 0);
            acc[1][0] = __builtin_amdgcn_mfma_f32_32x32x16_bf16(a1, b0, acc[1][0], 0, 0, 0);
            acc[1][1] = __builtin_amdgcn_mfma_f32_32x32x16_bf16(a1, b1, acc[1][1], 0, 0, 0);
        }
    }

#pragma unroll
    for (int mt = 0; mt < 2; ++mt)
#pragma unroll
        for (int nt = 0; nt < 2; ++nt) {
            const int n = n0 + 64 * wn + 32 * nt + col;
            const float bsv = bo[n];
#pragma unroll
            for (int r = 0; r < 16; ++r) {
                const int m = m0 + 64 * wm + 32 * mt + (r & 3) + 8 * (r >> 2) + 4 * g;
                Resid[(size_t)m * HID + n] = acc[mt][nt][r] + bsv + X[(size_t)m * HID + n];
            }
        }
}

// ---------------------------------------------------------------------------
// Kernel 4: LayerNorm.
// ---------------------------------------------------------------------------
__global__ __launch_bounds__(256) void ln_kernel(
    const float* __restrict__ Rin, const float* __restrict__ gamma,
    const float* __restrict__ beta, float* __restrict__ Out)
{
    const int row = blockIdx.x;
    const int t   = threadIdx.x;
    const float* __restrict__ x = Rin + (size_t)row * HID;

    const float v0 = x[t];
    const float v1 = x[t + 256];
    const float v2 = x[t + 512];
    float s  = v0 + v1 + v2;
    float s2 = v0 * v0 + v1 * v1 + v2 * v2;
#pragma unroll
    for (int off = 32; off; off >>= 1) {
        s  += __shfl_xor(s,  off, 64);
        s2 += __shfl_xor(s2, off, 64);
    }
    __shared__ float rs[4], rs2[4];
    const int w = t >> 6, lane = t & 63;
    if (lane == 0) { rs[w] = s; rs2[w] = s2; }
    __syncthreads();
    const float tot  = rs[0] + rs[1] + rs[2] + rs[3];
    const float tot2 = rs2[0] + rs2[1] + rs2[2] + rs2[3];
    const float mu   = tot * (1.0f / HID);
    const float var  = tot2 * (1.0f / HID) - mu * mu;
    const float rsig = rsqrtf(var + 1e-5f);

    float* __restrict__ y = Out + (size_t)row * HID;
    y[t]       = (v0 - mu) * rsig * gamma[t]       + beta[t];
    y[t + 256] = (v1 - mu) * rsig * gamma[t + 256] + beta[t + 256];
    y[t + 512] = (v2 - mu) * rsig * gamma[t + 512] + beta[t + 512];
}

// ---------------------------------------------------------------------------
extern "C" void kernel_launch(void* const* d_in, const int* in_sizes, int n_in,
                              void* d_out, int out_size, void* d_ws, size_t ws_size,
                              hipStream_t stream)
{
    const float* X     = (const float*)d_in[0];
    const float* mask  = (const float*)d_in[1];
    const float* Wq    = (const float*)d_in[2];
    const float* bq    = (const float*)d_in[3];
    const float* Wk    = (const float*)d_in[4];
    const float* bk    = (const float*)d_in[5];
    const float* Wv    = (const float*)d_in[6];
    const float* bv    = (const float*)d_in[7];
    const float* Wo    = (const float*)d_in[8];
    const float* bo    = (const float*)d_in[9];
    const float* gamma = (const float*)d_in[10];
    const float* beta  = (const float*)d_in[11];
    float* out = (float*)d_out;

    const size_t N = (size_t)MTOT * HID;        // 6,291,456 elements
    const size_t WTE = (size_t)4 * HID * HID;

    char* p = (char*)d_ws;
    __hip_bfloat16* Xb  = (__hip_bfloat16*)p;  p += 2 * N;
    __hip_bfloat16* Wt  = (__hip_bfloat16*)p;  p += 2 * WTE;
    __hip_bfloat16* Qw  = (__hip_bfloat16*)p;  p += 2 * N;
    __hip_bfloat16* Kw  = (__hip_bfloat16*)p;  p += 2 * N;
    __hip_bfloat16* Vtw = (__hip_bfloat16*)p;  p += 2 * N;
    char* opb = p;
    const size_t fixed = (size_t)(opb - (char*)d_ws);

    const size_t lpsz4 = 4 * (size_t)(BB * NHEADS) * SEQ * sizeof(float);
    const int KS = (ws_size >= fixed + 4 * 2 * N + lpsz4) ? 4 : 2;

    __hip_bfloat16* Op  = (__hip_bfloat16*)opb;          // KS*N bf16 partial O
    float* lpt = (float*)(opb + (size_t)KS * 2 * N);     // KS*24*SEQ fp32
    __hip_bfloat16* Ctxb = Xb;      // Xb dead after qkv
    float* Rd = (float*)Kw;         // Kw+Vtw dead after attn: exactly N fp32

    cast_x_kernel<<<(int)(N / 2048), 256, 0, stream>>>(X, Xb);
    pack_w_kernel<<<dim3(12, 12, 4), 256, 0, stream>>>(Wq, Wk, Wv, Wo, Wt);
    qkv_mfma_kernel<<<dim3(18, MTOT / 128), 256, 0, stream>>>(
        Xb, Wt, bq, bk, bv, Qw, Kw, Vtw);
    attn_kernel<<<dim3(SEQ / 256, BB * NHEADS, KS), 256, 0, stream>>>(
        Qw, Kw, Vtw, mask, Op, lpt);
    combine_kernel<<<(int)(N / 2048), 256, 0, stream>>>(Op, lpt, Ctxb, KS);
    out_mfma_kernel<<<dim3(6, MTOT / 128), 256, 0, stream>>>(
        Ctxb, Wt + (size_t)2304 * HID, bo, X, Rd);
    ln_kernel<<<MTOT, 256, 0, stream>>>(Rd, gamma, beta, out);
}

// Round 7
// 328.023 us; speedup vs baseline: 6.4288x; 6.4288x over previous
//
#include <hip/hip_runtime.h>
#include <hip/hip_bf16.h>

#define HID 768
#define NHEADS 12
#define HDIM 64
#define SEQ 4096
#define BB 2
#define MTOT (BB * SEQ)   // 8192 rows

typedef __attribute__((ext_vector_type(8))) short bf16x8;
typedef __attribute__((ext_vector_type(16))) float f32x16;

#define LOG2E 1.4426950408889634f

__device__ inline unsigned pack2bf(float a, float b) {
    __hip_bfloat162 h = __float22bfloat162_rn(float2{a, b});
    return *(unsigned*)&h;
}

// ---------------------------------------------------------------------------
// Kernel 0a: cast X fp32 -> bf16. grid 3072, block 256, 8 elems/thread.
// ---------------------------------------------------------------------------
__global__ __launch_bounds__(256) void cast_x_kernel(
    const float* __restrict__ X, __hip_bfloat16* __restrict__ Xb)
{
    const size_t i = ((size_t)blockIdx.x * 256 + threadIdx.x) * 8;
    const float4 x0 = *(const float4*)(X + i);
    const float4 x1 = *(const float4*)(X + i + 4);
    unsigned u[4];
    u[0] = pack2bf(x0.x, x0.y);
    u[1] = pack2bf(x0.z, x0.w);
    u[2] = pack2bf(x1.x, x1.y);
    u[3] = pack2bf(x1.z, x1.w);
    *(uint4*)(Xb + i) = *(uint4*)u;
}

// ---------------------------------------------------------------------------
// Kernel 0b: pack weights: W[in][out] fp32 -> Wt[out(global)][in] bf16.
// z=0..3 selects Wq,Wk,Wv,Wo; Wo at row offset 2304.
// ---------------------------------------------------------------------------
__global__ __launch_bounds__(256) void pack_w_kernel(
    const float* __restrict__ Wq, const float* __restrict__ Wk,
    const float* __restrict__ Wv, const float* __restrict__ Wo,
    __hip_bfloat16* __restrict__ Wt)
{
    const int z = blockIdx.z;
    const float* __restrict__ W = (z == 0) ? Wq : (z == 1) ? Wk : (z == 2) ? Wv : Wo;
    const int in0  = blockIdx.x * 64;
    const int out0 = blockIdx.y * 64;
    const int t = threadIdx.x;

    __shared__ float T[64][65];
#pragma unroll
    for (int i = 0; i < 4; ++i) {
        const int idx = t + 256 * i;
        const int row = idx >> 4;
        const int c4  = (idx & 15) << 2;
        const float4 v = *(const float4*)(W + (size_t)(in0 + row) * HID + out0 + c4);
        T[row][c4 + 0] = v.x; T[row][c4 + 1] = v.y;
        T[row][c4 + 2] = v.z; T[row][c4 + 3] = v.w;
    }
    __syncthreads();

    const int o  = t >> 2;
    const int cb = (t & 3) << 4;
    __hip_bfloat16 tmp[16];
#pragma unroll
    for (int k = 0; k < 16; ++k)
        tmp[k] = __float2bfloat16(T[cb + k][o]);
    __hip_bfloat16* __restrict__ dst =
        Wt + (size_t)(z * HID + out0 + o) * HID + in0 + cb;
    *(uint4*)(dst)     = *(uint4*)(&tmp[0]);
    *(uint4*)(dst + 8) = *(uint4*)(&tmp[8]);
}

// ---------------------------------------------------------------------------
// Kernel 1: fused QKV MFMA GEMM. Q,K -> bf16 [b,h,s,64]; V -> bf16 [b,h,64,s]
// (transposed in-epilogue via LDS). grid (18, 64), block 256, 128x128, BK=64.
// ---------------------------------------------------------------------------
__global__ __launch_bounds__(256) void qkv_mfma_kernel(
    const __hip_bfloat16* __restrict__ Xb, const __hip_bfloat16* __restrict__ Wt,
    const float* __restrict__ bq, const float* __restrict__ bk,
    const float* __restrict__ bv,
    __hip_bfloat16* __restrict__ Qo, __hip_bfloat16* __restrict__ Ko,
    __hip_bfloat16* __restrict__ Vo)
{
    const int nblk = blockIdx.x;          // 0..17
    const int z  = nblk / 6;              // 0=Q,1=K,2=V
    const int f0 = (nblk % 6) * 128;      // feature base within segment
    const int n0 = nblk * 128;            // row base in Wt
    const int m0 = blockIdx.y * 128;

    const float* __restrict__ bias = (z == 0) ? bq : (z == 1) ? bk : bv;

    const int t    = threadIdx.x;
    const int w    = t >> 6;
    const int lane = t & 63;
    const int col  = lane & 31;
    const int g    = lane >> 5;
    const int wm   = w & 1;
    const int wn   = w >> 1;

    __shared__ __hip_bfloat16 smem[2 * 128 * 72];   // As | Bs; Ts overlays both
    __hip_bfloat16 (*As)[72] = (__hip_bfloat16(*)[72])smem;
    __hip_bfloat16 (*Bs)[72] = (__hip_bfloat16(*)[72])(smem + 128 * 72);

    f32x16 acc[2][2];
#pragma unroll
    for (int mt = 0; mt < 2; ++mt)
#pragma unroll
        for (int nt = 0; nt < 2; ++nt)
#pragma unroll
            for (int r = 0; r < 16; ++r) acc[mt][nt][r] = 0.f;

    for (int k0 = 0; k0 < HID; k0 += 64) {
        __syncthreads();
#pragma unroll
        for (int i = 0; i < 4; ++i) {
            const int idx = t + 256 * i;     // 0..1023
            const int row = idx >> 3;        // 0..127
            const int c8  = (idx & 7) << 3;  // 0..56
            *(uint4*)&As[row][c8] = *(const uint4*)(Xb + (size_t)(m0 + row) * HID + k0 + c8);
            *(uint4*)&Bs[row][c8] = *(const uint4*)(Wt + (size_t)(n0 + row) * HID + k0 + c8);
        }
        __syncthreads();
#pragma unroll
        for (int kh = 0; kh < 4; ++kh) {
            const int ko = 16 * kh + 8 * g;
            const bf16x8 a0 = *(const bf16x8*)&As[64 * wm + col][ko];
            const bf16x8 a1 = *(const bf16x8*)&As[64 * wm + 32 + col][ko];
            const bf16x8 b0 = *(const bf16x8*)&Bs[64 * wn + col][ko];
            const bf16x8 b1 = *(const bf16x8*)&Bs[64 * wn + 32 + col][ko];
            acc[0][0] = __builtin_amdgcn_mfma_f32_32x32x16_bf16(a0, b0, acc[0][0], 0, 0, 0);
            acc[0][1] = __builtin_amdgcn_mfma_f32_32x32x16_bf16(a0, b1, acc[0][1], 0, 0, 0);
            acc[1][0] = __builtin_amdgcn_mfma_f32_32x32x16_bf16(a1, b0, acc[1][0], 0, 0, 0);
            acc[1][1] = __builtin_amdgcn_mfma_f32_32x32x16_bf16(a1, b1, acc[1][1], 0, 0, 0);
        }
    }

    if (z < 2) {
        __hip_bfloat16* __restrict__ Out = (z == 0) ? Qo : Ko;
        const int h = (f0 >> 6) + wn;
#pragma unroll
        for (int mt = 0; mt < 2; ++mt)
#pragma unroll
            for (int nt = 0; nt < 2; ++nt) {
                const int d = 32 * nt + col;
                const float bsv = bias[f0 + 64 * wn + d];
#pragma unroll
                for (int r = 0; r < 16; ++r) {
                    const int m = m0 + 64 * wm + 32 * mt + (r & 3) + 8 * (r >> 2) + 4 * g;
                    const int b = m >> 12;
                    const int s = m & (SEQ - 1);
                    Out[(((size_t)(b * NHEADS + h)) * SEQ + s) * HDIM + d] =
                        __float2bfloat16(acc[mt][nt][r] + bsv);
                }
            }
    } else {
        // V: transpose 128x128 tile via LDS, write Vt [bh][d][s]
        __syncthreads();   // K-loop LDS reads done before overlay
        __hip_bfloat16 (*Ts)[136] = (__hip_bfloat16(*)[136])smem;  // 34816 B
#pragma unroll
        for (int mt = 0; mt < 2; ++mt)
#pragma unroll
            for (int nt = 0; nt < 2; ++nt) {
                const int nloc = 64 * wn + 32 * nt + col;
                const float bsv = bias[f0 + nloc];
#pragma unroll
                for (int rg = 0; rg < 4; ++rg) {
                    const int mbase = 64 * wm + 32 * mt + 8 * rg + 4 * g;
                    unsigned pu[2];
                    pu[0] = pack2bf(acc[mt][nt][4 * rg + 0] + bsv,
                                    acc[mt][nt][4 * rg + 1] + bsv);
                    pu[1] = pack2bf(acc[mt][nt][4 * rg + 2] + bsv,
                                    acc[mt][nt][4 * rg + 3] + bsv);
                    *(uint2*)&Ts[nloc][mbase] = *(uint2*)pu;
                }
            }
        __syncthreads();
        const int nloc = t >> 1;
        const int half = t & 1;
        const int hh = (f0 >> 6) + (nloc >> 6);
        const int d  = nloc & 63;
        const int bb = m0 >> 12;
        const int s0 = m0 & (SEQ - 1);
        __hip_bfloat16* __restrict__ dst =
            Vo + (((size_t)(bb * NHEADS + hh)) * HDIM + d) * SEQ + s0 + 64 * half;
        const __hip_bfloat16* srcp = &Ts[nloc][64 * half];
#pragma unroll
        for (int j = 0; j < 8; ++j)
            *(uint4*)(dst + 8 * j) = *(const uint4*)(srcp + 8 * j);
    }
}

// ---------------------------------------------------------------------------
// Kernel 2: MFMA flash attention (S^T-swap + shuffle P-transform, K-split).
// exp2-folded softmax, no clamp. launch_bounds(256,2): this kernel's unified
// VGPR+acc footprint (~184 regs) cannot fit >2 waves/SIMD — (256,4) spilled
// accumulators to scratch (6.9 GB HBM traffic, 12x regression, round 6).
// ---------------------------------------------------------------------------
__global__ __launch_bounds__(256, 2) void attn_kernel(
    const __hip_bfloat16* __restrict__ Qb, const __hip_bfloat16* __restrict__ Kb,
    const __hip_bfloat16* __restrict__ Vt, const float* __restrict__ mask,
    __hip_bfloat16* __restrict__ Op, float* __restrict__ lp)
{
    const int bh = blockIdx.y;
    const int b  = bh / NHEADS;
    const int h  = bh - b * NHEADS;
    const int kspan = SEQ / gridDim.z;
    const int kbeg  = blockIdx.z * kspan;

    const int t    = threadIdx.x;
    const int w    = t >> 6;
    const int lane = t & 63;
    const int col  = lane & 31;
    const int g    = lane >> 5;
    const int qw   = blockIdx.x * 256 + 64 * w;

    __shared__ __hip_bfloat16 Ks[64][72];
    __shared__ __hip_bfloat16 Vts[64][72];
    __shared__ float madd[64];   // premultiplied by log2(e)

    const __hip_bfloat16* __restrict__ Qh = Qb + (size_t)bh * SEQ * HDIM;
    const __hip_bfloat16* __restrict__ Kh = Kb + (size_t)bh * SEQ * HDIM;
    const __hip_bfloat16* __restrict__ Vh = Vt + (size_t)bh * HDIM * SEQ;

    bf16x8 bq[2][4];
#pragma unroll
    for (int mt = 0; mt < 2; ++mt)
#pragma unroll
        for (int kh = 0; kh < 4; ++kh)
            bq[mt][kh] = *(const bf16x8*)(Qh + (size_t)(qw + 32 * mt + col) * HDIM
                                          + 16 * kh + 8 * g);

    f32x16 O[2][2];
    float lac[2] = {0.f, 0.f};
#pragma unroll
    for (int mt = 0; mt < 2; ++mt)
#pragma unroll
        for (int dt = 0; dt < 2; ++dt)
#pragma unroll
            for (int r = 0; r < 16; ++r) O[mt][dt][r] = 0.f;

    const float kscale = 0.125f * LOG2E;

    for (int kt0 = 0; kt0 < kspan; kt0 += 64) {
        const int kt = kbeg + kt0;
        __syncthreads();
#pragma unroll
        for (int i = 0; i < 2; ++i) {
            const int idx = t + 256 * i;
            const int row = idx >> 3;
            const int c8  = (idx & 7) << 3;
            *(uint4*)&Ks[row][c8]  = *(const uint4*)(Kh + (size_t)(kt + row) * HDIM + c8);
            *(uint4*)&Vts[row][c8] = *(const uint4*)(Vh + (size_t)row * SEQ + kt + c8);
        }
        if (t < 64) madd[t] = (1.0f - mask[b * SEQ + kt + t]) * (-10000.0f * LOG2E);
        __syncthreads();

        f32x16 St[2][2];
#pragma unroll
        for (int mt = 0; mt < 2; ++mt)
#pragma unroll
            for (int nt = 0; nt < 2; ++nt)
#pragma unroll
                for (int r = 0; r < 16; ++r) St[mt][nt][r] = 0.f;

#pragma unroll
        for (int kh = 0; kh < 4; ++kh) {
            const bf16x8 ak0 = *(const bf16x8*)&Ks[col][16 * kh + 8 * g];
            const bf16x8 ak1 = *(const bf16x8*)&Ks[32 + col][16 * kh + 8 * g];
            St[0][0] = __builtin_amdgcn_mfma_f32_32x32x16_bf16(ak0, bq[0][kh], St[0][0], 0, 0, 0);
            St[1][0] = __builtin_amdgcn_mfma_f32_32x32x16_bf16(ak0, bq[1][kh], St[1][0], 0, 0, 0);
            St[0][1] = __builtin_amdgcn_mfma_f32_32x32x16_bf16(ak1, bq[0][kh], St[0][1], 0, 0, 0);
            St[1][1] = __builtin_amdgcn_mfma_f32_32x32x16_bf16(ak1, bq[1][kh], St[1][1], 0, 0, 0);
        }

#pragma unroll
        for (int mt = 0; mt < 2; ++mt) {
            unsigned g4x[2][4], g4y[2][4];
#pragma unroll
            for (int nt = 0; nt < 2; ++nt) {
#pragma unroll
                for (int b4 = 0; b4 < 4; ++b4) {
                    const float4 mm = *(const float4*)&madd[32 * nt + 8 * b4 + 4 * g];
                    const float p0 = __builtin_amdgcn_exp2f(fmaf(St[mt][nt][4 * b4 + 0], kscale, mm.x));
                    const float p1 = __builtin_amdgcn_exp2f(fmaf(St[mt][nt][4 * b4 + 1], kscale, mm.y));
                    const float p2 = __builtin_amdgcn_exp2f(fmaf(St[mt][nt][4 * b4 + 2], kscale, mm.z));
                    const float p3 = __builtin_amdgcn_exp2f(fmaf(St[mt][nt][4 * b4 + 3], kscale, mm.w));
                    lac[mt] += (p0 + p1) + (p2 + p3);
                    g4x[nt][b4] = pack2bf(p0, p1);
                    g4y[nt][b4] = pack2bf(p2, p3);
                }
            }
#pragma unroll
            for (int kh = 0; kh < 4; ++kh) {
                const int nt  = kh >> 1;
                const int khl = kh & 1;
                const unsigned lo_x = g4x[nt][2 * khl],     lo_y = g4y[nt][2 * khl];
                const unsigned hi_x = g4x[nt][2 * khl + 1], hi_y = g4y[nt][2 * khl + 1];
                const unsigned sx = g ? lo_x : hi_x;
                const unsigned sy = g ? lo_y : hi_y;
                const unsigned rx = (unsigned)__shfl_xor((int)sx, 32, 64);
                const unsigned ry = (unsigned)__shfl_xor((int)sy, 32, 64);
                union { unsigned u[4]; bf16x8 v; } au;
                if (g) { au.u[0] = rx; au.u[1] = ry; au.u[2] = hi_x; au.u[3] = hi_y; }
                else   { au.u[0] = lo_x; au.u[1] = lo_y; au.u[2] = rx; au.u[3] = ry; }
                const bf16x8 bv0 = *(const bf16x8*)&Vts[col][16 * kh + 8 * g];
                const bf16x8 bv1 = *(const bf16x8*)&Vts[32 + col][16 * kh + 8 * g];
                O[mt][0] = __builtin_amdgcn_mfma_f32_32x32x16_bf16(au.v, bv0, O[mt][0], 0, 0, 0);
                O[mt][1] = __builtin_amdgcn_mfma_f32_32x32x16_bf16(au.v, bv1, O[mt][1], 0, 0, 0);
            }
        }
    }

    const size_t opbase = (size_t)blockIdx.z * ((size_t)MTOT * HID);
#pragma unroll
    for (int mt = 0; mt < 2; ++mt) {
        const float l = lac[mt] + __shfl_xor(lac[mt], 32, 64);
        if (g == 0)
            lp[((size_t)blockIdx.z * (BB * NHEADS) + bh) * SEQ + qw + 32 * mt + col] = l;
#pragma unroll
        for (int dt = 0; dt < 2; ++dt)
#pragma unroll
            for (int r = 0; r < 16; ++r) {
                const int q = qw + 32 * mt + (r & 3) + 8 * (r >> 2) + 4 * g;
                const int d = 32 * dt + col;
                Op[opbase + ((size_t)b * SEQ + q) * HID + h * HDIM + d] =
                    __float2bfloat16(O[mt][dt][r]);
            }
    }
}

// ---------------------------------------------------------------------------
// Kernel 2b: combine K-split partials -> Ctx bf16. 8 elems/thread.
// ---------------------------------------------------------------------------
__global__ __launch_bounds__(256) void combine_kernel(
    const __hip_bfloat16* __restrict__ Op, const float* __restrict__ lp,
    __hip_bfloat16* __restrict__ Ctx, int KS)
{
    const size_t i = ((size_t)blockIdx.x * 256 + threadIdx.x) * 8;
    const int n   = (int)(i % HID);
    const int row = (int)(i / HID);
    const int h = n >> 6;
    const int b = row >> 12;
    const int q = row & (SEQ - 1);
    const int bh = b * NHEADS + h;

    float denom = 0.f;
    float o[8] = {};
    for (int kz = 0; kz < KS; ++kz) {
        denom += lp[((size_t)kz * (BB * NHEADS) + bh) * SEQ + q];
        uint4 u = *(const uint4*)(Op + (size_t)kz * ((size_t)MTOT * HID) + i);
        const __hip_bfloat16* e = (const __hip_bfloat16*)&u;
#pragma unroll
        for (int j = 0; j < 8; ++j) o[j] += __bfloat162float(e[j]);
    }
    const float inv = 1.0f / denom;
    unsigned u[4];
#pragma unroll
    for (int j = 0; j < 4; ++j)
        u[j] = pack2bf(o[2 * j] * inv, o[2 * j + 1] * inv);
    *(uint4*)(Ctx + i) = *(uint4*)u;
}

// ---------------------------------------------------------------------------
// Kernel 3: output projection MFMA + bias + residual -> Resid fp32.
// grid (6, 64), block 256.
// ---------------------------------------------------------------------------
__global__ __launch_bounds__(256) void out_mfma_kernel(
    const __hip_bfloat16* __restrict__ Cb, const __hip_bfloat16* __restrict__ Wto,
    const float* __restrict__ bo, const float* __restrict__ X,
    float* __restrict__ Resid)
{
    const int n0 = blockIdx.x * 128;
    const int m0 = blockIdx.y * 128;

    const int t    = threadIdx.x;
    const int w    = t >> 6;
    const int lane = t & 63;
    const int col  = lane & 31;
    const int g    = lane >> 5;
    const int wm   = w & 1;
    const int wn   = w >> 1;

    __shared__ __hip_bfloat16 As[128][72];
    __shared__ __hip_bfloat16 Bs[128][72];

    f32x16 acc[2][2];
#pragma unroll
    for (int mt = 0; mt < 2; ++mt)
#pragma unroll
        for (int nt = 0; nt < 2; ++nt)
#pragma unroll
            for (int r = 0; r < 16; ++r) acc[mt][nt][r] = 0.f;

    for (int k0 = 0; k0 < HID; k0 += 64) {
        __syncthreads();
#pragma unroll
        for (int i = 0; i < 4; ++i) {
            const int idx = t + 256 * i;
            const int row = idx >> 3;
            const int c8  = (idx & 7) << 3;
            *(uint4*)&As[row][c8] = *(const uint4*)(Cb  + (size_t)(m0 + row) * HID + k0 + c8);
            *(uint4*)&Bs[row][c8] = *(const uint4*)(Wto + (size_t)(n0 + row) * HID + k0 + c8);
        }
        __syncthreads();
#pragma unroll
        for (int kh = 0; kh < 4; ++kh) {
            const int ko = 16 * kh + 8 * g;
            const bf16x8 a0 = *(const bf16x8*)&As[64 * wm + col][ko];
            const bf16x8 a1 = *(const bf16x8*)&As[64 * wm + 32 + col][ko];
            const bf16x8 b0 = *(const bf16x8*)&Bs[64 * wn + col][ko];
            const bf16x8 b1 = *(const bf16x8*)&Bs[64 * wn + 32 + col][ko];
            acc[0][0] = __builtin_amdgcn_mfma_f32_32x32x16_bf16(a0, b0, acc[0][0], 0, 0, 0);
            acc[0][1] = __builtin_amdgcn_mfma_f32_32x32x16_bf16(a0, b1, acc[0][1], 0, 0, 0);
            acc[1][0] = __builtin_amdgcn_mfma_f32_32x32x16_bf16(a1, b0, acc[1][0], 0, 0, 0);
            acc[1][1] = __builtin_amdgcn_mfma_f32_32x32x16_bf16(a1, b1, acc[1][1], 0, 0, 0);
        }
    }

#pragma unroll
    for (int mt = 0; mt < 2; ++mt)
#pragma unroll
        for (int nt = 0; nt < 2; ++nt) {
            const int n = n0 + 64 * wn + 32 * nt + col;
            const float bsv = bo[n];
#pragma unroll
            for (int r = 0; r < 16; ++r) {
                const int m = m0 + 64 * wm + 32 * mt + (r & 3) + 8 * (r >> 2) + 4 * g;
                Resid[(size_t)m * HID + n] = acc[mt][nt][r] + bsv + X[(size_t)m * HID + n];
            }
        }
}

// ---------------------------------------------------------------------------
// Kernel 4: LayerNorm.
// ---------------------------------------------------------------------------
__global__ __launch_bounds__(256) void ln_kernel(
    const float* __restrict__ Rin, const float* __restrict__ gamma,
    const float* __restrict__ beta, float* __restrict__ Out)
{
    const int row = blockIdx.x;
    const int t   = threadIdx.x;
    const float* __restrict__ x = Rin + (size_t)row * HID;

    const float v0 = x[t];
    const float v1 = x[t + 256];
    const float v2 = x[t + 512];
    float s  = v0 + v1 + v2;
    float s2 = v0 * v0 + v1 * v1 + v2 * v2;
#pragma unroll
    for (int off = 32; off; off >>= 1) {
        s  += __shfl_xor(s,  off, 64);
        s2 += __shfl_xor(s2, off, 64);
    }
    __shared__ float rs[4], rs2[4];
    const int w = t >> 6, lane = t & 63;
    if (lane == 0) { rs[w] = s; rs2[w] = s2; }
    __syncthreads();
    const float tot  = rs[0] + rs[1] + rs[2] + rs[3];
    const float tot2 = rs2[0] + rs2[1] + rs2[2] + rs2[3];
    const float mu   = tot * (1.0f / HID);
    const float var  = tot2 * (1.0f / HID) - mu * mu;
    const float rsig = rsqrtf(var + 1e-5f);

    float* __restrict__ y = Out + (size_t)row * HID;
    y[t]       = (v0 - mu) * rsig * gamma[t]       + beta[t];
    y[t + 256] = (v1 - mu) * rsig * gamma[t + 256] + beta[t + 256];
    y[t + 512] = (v2 - mu) * rsig * gamma[t + 512] + beta[t + 512];
}

// ---------------------------------------------------------------------------
extern "C" void kernel_launch(void* const* d_in, const int* in_sizes, int n_in,
                              void* d_out, int out_size, void* d_ws, size_t ws_size,
                              hipStream_t stream)
{
    const float* X     = (const float*)d_in[0];
    const float* mask  = (const float*)d_in[1];
    const float* Wq    = (const float*)d_in[2];
    const float* bq    = (const float*)d_in[3];
    const float* Wk    = (const float*)d_in[4];
    const float* bk    = (const float*)d_in[5];
    const float* Wv    = (const float*)d_in[6];
    const float* bv    = (const float*)d_in[7];
    const float* Wo    = (const float*)d_in[8];
    const float* bo    = (const float*)d_in[9];
    const float* gamma = (const float*)d_in[10];
    const float* beta  = (const float*)d_in[11];
    float* out = (float*)d_out;

    const size_t N = (size_t)MTOT * HID;        // 6,291,456 elements
    const size_t WTE = (size_t)4 * HID * HID;

    char* p = (char*)d_ws;
    __hip_bfloat16* Xb  = (__hip_bfloat16*)p;  p += 2 * N;
    __hip_bfloat16* Wt  = (__hip_bfloat16*)p;  p += 2 * WTE;
    __hip_bfloat16* Qw  = (__hip_bfloat16*)p;  p += 2 * N;
    __hip_bfloat16* Kw  = (__hip_bfloat16*)p;  p += 2 * N;
    __hip_bfloat16* Vtw = (__hip_bfloat16*)p;  p += 2 * N;
    char* opb = p;
    const size_t fixed = (size_t)(opb - (char*)d_ws);

    const size_t lpsz4 = 4 * (size_t)(BB * NHEADS) * SEQ * sizeof(float);
    const int KS = (ws_size >= fixed + 4 * 2 * N + lpsz4) ? 4 : 2;

    __hip_bfloat16* Op  = (__hip_bfloat16*)opb;          // KS*N bf16 partial O
    float* lpt = (float*)(opb + (size_t)KS * 2 * N);     // KS*24*SEQ fp32
    __hip_bfloat16* Ctxb = Xb;      // Xb dead after qkv
    float* Rd = (float*)Kw;         // Kw+Vtw dead after attn: exactly N fp32

    cast_x_kernel<<<(int)(N / 2048), 256, 0, stream>>>(X, Xb);
    pack_w_kernel<<<dim3(12, 12, 4), 256, 0, stream>>>(Wq, Wk, Wv, Wo, Wt);
    qkv_mfma_kernel<<<dim3(18, MTOT / 128), 256, 0, stream>>>(
        Xb, Wt, bq, bk, bv, Qw, Kw, Vtw);
    attn_kernel<<<dim3(SEQ / 256, BB * NHEADS, KS), 256, 0, stream>>>(
        Qw, Kw, Vtw, mask, Op, lpt);
    combine_kernel<<<(int)(N / 2048), 256, 0, stream>>>(Op, lpt, Ctxb, KS);
    out_mfma_kernel<<<dim3(6, MTOT / 128), 256, 0, stream>>>(
        Ctxb, Wt + (size_t)2304 * HID, bo, X, Rd);
    ln_kernel<<<MTOT, 256, 0, stream>>>(Rd, gamma, beta, out);
}